// Round 27
// baseline (104.209 us; speedup 1.0000x reference)
//
#include <hip/hip_runtime.h>
#include <stdint.h>

#define DI __device__ __forceinline__

typedef __attribute__((ext_vector_type(8))) __bf16 bfrag;   // MFMA A/B operand (4 VGPRs)
typedef __attribute__((ext_vector_type(4))) __bf16 bf16x4;
typedef __attribute__((ext_vector_type(4))) float f32x4;    // MFMA C/D operand

static constexpr int Bb = 8, Ss = 1024, Dd = 768, Hh = 12, DKk = 64;
static constexpr int Mm = Bb * Ss;          // 8192 rows

typedef __attribute__((address_space(3))) void lds_void_t;
typedef const __attribute__((address_space(1))) void gvoid_t;

DI void async_load16(const void* g, void* lds) {
    __builtin_amdgcn_global_load_lds((gvoid_t*)(uintptr_t)g,
                                     (lds_void_t*)(uint32_t)(uintptr_t)lds, 16, 0, 0);
}

#if __has_builtin(__builtin_amdgcn_exp2f)
#define EXP2(x) __builtin_amdgcn_exp2f(x)
#else
extern "C" __device__ float __ocml_exp2_f32(float);
#define EXP2(x) __ocml_exp2_f32(x)
#endif

// ---- fp32 -> bf16 convert, all 7 tensors in ONE launch ----
__global__ __launch_bounds__(256) void cvt_k(const float* __restrict__ a0, const float* __restrict__ a1,
                                             const float* __restrict__ a2,
                                             const float* __restrict__ w0, const float* __restrict__ w1,
                                             const float* __restrict__ w2, const float* __restrict__ w3,
                                             __bf16* __restrict__ da0, __bf16* __restrict__ da1,
                                             __bf16* __restrict__ da2,
                                             __bf16* __restrict__ dw0, __bf16* __restrict__ dw1,
                                             __bf16* __restrict__ dw2, __bf16* __restrict__ dw3) {
    const int bid = (int)blockIdx.x;
    const float* s; __bf16* d; int off;
    if (bid < 9216) {
        const int ti = bid / 3072;
        off = (bid % 3072) * 2048;
        s = ti == 0 ? a0 : ti == 1 ? a1 : a2;
        d = ti == 0 ? da0 : ti == 1 ? da1 : da2;
    } else {
        const int b2 = bid - 9216;
        const int ti = b2 / 288;
        off = (b2 % 288) * 2048;
        s = ti == 0 ? w0 : ti == 1 ? w1 : ti == 2 ? w2 : w3;
        d = ti == 0 ? dw0 : ti == 1 ? dw1 : ti == 2 ? dw2 : dw3;
    }
    const int i = off + (int)threadIdx.x * 8;
    f32x4 a = *(const f32x4*)(s + i);
    f32x4 b = *(const f32x4*)(s + i + 4);
    bfrag o;
#pragma unroll
    for (int j = 0; j < 4; ++j) { o[j] = (__bf16)a[j]; o[j + 4] = (__bf16)b[j]; }
    *(bfrag*)(d + i) = o;
}

// ---- GEMM core v6 (r19-proven): 128x128 tile, BK=64, 2-barrier loop,
// 512 threads = 8 waves, wave-tile 64x32. bf16 A via global_load_lds. ----
DI void gemm_core8(const __bf16* __restrict__ A, const __bf16* __restrict__ W,
                   __bf16* As, __bf16* Bs, int row0, int col0, int t, f32x4 acc[4][2]) {
    const int lane = t & 63, w = t >> 6;          // w = 0..7
    const int l15 = lane & 15, lg = lane >> 4;
    const int wr = (w >> 2) * 64, wc = (w & 3) * 32;
    const int rl = lane >> 3, clin = lane & 7;    // staging: row-in-op, linear chunk

    for (int k0 = 0; k0 < 768; k0 += 64) {
        __syncthreads();   // all waves done reading previous tile
#pragma unroll
        for (int o = 0; o < 2; ++o) {
            const int g = w * 2 + o;              // op id 0..15, wave-uniform
            const int r = g * 8 + rl;             // tile row 0..127
            const int cg = clin ^ (r & 7);        // pre-swizzled global chunk
            async_load16(A + (size_t)(row0 + r) * Dd + k0 + cg * 8, As + g * 512);
            async_load16(W + (size_t)(col0 + r) * Dd + k0 + cg * 8, Bs + g * 512);
        }
        __syncthreads();   // compiler drains vmcnt before barrier -> LDS visible

        bfrag af[4][2], bf[2][2];
#pragma unroll
        for (int mi = 0; mi < 4; ++mi) {
            const int ra = wr + mi * 16 + l15;
#pragma unroll
            for (int ks = 0; ks < 2; ++ks)
                af[mi][ks] = *(const bfrag*)(As + ra * 64 + (((ks * 4 + lg) ^ (ra & 7)) * 8));
        }
#pragma unroll
        for (int ni = 0; ni < 2; ++ni) {
            const int rb = wc + ni * 16 + l15;
#pragma unroll
            for (int ks = 0; ks < 2; ++ks)
                bf[ni][ks] = *(const bfrag*)(Bs + rb * 64 + (((ks * 4 + lg) ^ (rb & 7)) * 8));
        }
#pragma unroll
        for (int mi = 0; mi < 4; ++mi)
#pragma unroll
            for (int ni = 0; ni < 2; ++ni)
#pragma unroll
                for (int ks = 0; ks < 2; ++ks)
                    acc[mi][ni] = __builtin_amdgcn_mfma_f32_16x16x32_bf16(af[mi][ks], bf[ni][ks],
                                                                          acc[mi][ni], 0, 0, 0);
    }
}

// ---- fused QKV projection: 1-D grid 1152, 512 threads, T1 XCD-bijective
// with Z-INTERLEAVE: z = l%3, r2 = l/3 (bijective). Each XCD now gets an
// equal Q/K/V mix over the SAME contiguous A-row-panel range (the old z=l/384
// put all heavy V^T-epilogue blocks on XCDs 5-7 -> static imbalance).
// z=0: Q (scaled 0.125*log2e); z=1: K; z=2: V -> V^T [B,H,64,S].
__global__ __launch_bounds__(512) void qkv_gemm(const __bf16* __restrict__ qA, const __bf16* __restrict__ kA,
                                                const __bf16* __restrict__ vA,
                                                const __bf16* __restrict__ qW, const __bf16* __restrict__ kW,
                                                const __bf16* __restrict__ vW,
                                                const float* __restrict__ qb, const float* __restrict__ kb,
                                                const float* __restrict__ vb,
                                                __bf16* __restrict__ qO, __bf16* __restrict__ kO,
                                                __bf16* __restrict__ vO) {
    __shared__ __attribute__((aligned(16))) char smem[32768];
    __bf16* As = (__bf16*)smem;
    __bf16* Bs = (__bf16*)(smem + 16384);

    const int h = (int)blockIdx.x;
    const int l = (h & 7) * 144 + (h >> 3);      // 1152 % 8 == 0: bijective
    const int z = l % 3, r2 = l / 3;             // z-interleaved (load balance)
    const int row0 = (r2 / 6) * 128, col0 = (r2 % 6) * 128;

    const __bf16* A = z == 0 ? qA : z == 1 ? kA : vA;
    const __bf16* W = z == 0 ? qW : z == 1 ? kW : vW;
    const float* bias = z == 0 ? qb : z == 1 ? kb : vb;
    __bf16* O = z == 0 ? qO : z == 1 ? kO : vO;

    const int t = (int)threadIdx.x;
    const int lane = t & 63, w = t >> 6;
    const int l15 = lane & 15, lg = lane >> 4;
    const int wr = (w >> 2) * 64, wc = (w & 3) * 32;

    f32x4 acc[4][2] = {};
    gemm_core8(A, W, As, Bs, row0, col0, t, acc);

    if (z == 2) {
        // V^T epilogue, two half-passes over d-cols. Half dh covers cols
        // dh*64..dh*64+63; waves with (w&2)>>1 == dh hold them.
        auto T = reinterpret_cast<__bf16(*)[136]>(smem);   // [64 d][136 pad s]
        const int bb2 = row0 >> 10, sb = row0 & 1023;
#pragma unroll
        for (int dh = 0; dh < 2; ++dh) {
            __syncthreads();
            if (((w >> 1) & 1) == dh) {
#pragma unroll
                for (int mi = 0; mi < 4; ++mi)
#pragma unroll
                    for (int ni = 0; ni < 2; ++ni) {
                        const int dcol = (w & 1) * 32 + ni * 16 + l15;   // 0..63 in half
                        const float bv = bias[col0 + dh * 64 + dcol];
#pragma unroll
                        for (int j = 0; j < 4; ++j)
                            T[dcol][wr + mi * 16 + lg * 4 + j] = (__bf16)(acc[mi][ni][j] + bv);
                    }
            }
            __syncthreads();
#pragma unroll
            for (int it = 0; it < 2; ++it) {
                const int ld = it * 32 + (t >> 4);                 // 0..63
                const int cs = (t & 15) * 8;                       // s-chunk
                const int col = col0 + dh * 64 + ld;
                const int head = col >> 6, dd = col & 63;
                __bf16* dst = O + ((size_t)(bb2 * Hh + head) * DKk + dd) * Ss + sb + cs;
                *reinterpret_cast<bfrag*>(dst) = *reinterpret_cast<const bfrag*>(&T[ld][cs]);
            }
        }
    } else {
        const float scl = (z == 0) ? 0.18033688f : 1.0f;  // 0.125 * log2(e)
#pragma unroll
        for (int mi = 0; mi < 4; ++mi) {
#pragma unroll
            for (int ni = 0; ni < 2; ++ni) {
                const int cg = col0 + wc + ni * 16 + l15;
                const float bv = bias[cg];
#pragma unroll
                for (int j = 0; j < 4; ++j) {
                    const int rg = row0 + wr + mi * 16 + lg * 4 + j;
                    const float val = (acc[mi][ni][j] + bv) * scl;
                    const int bb = rg >> 10, ss = rg & 1023;
                    const int hh2 = cg >> 6, dd = cg & 63;
                    O[((size_t)(bb * Hh + hh2) * Ss + ss) * DKk + dd] = (__bf16)val;
                }
            }
        }
    }
}

// ---- output projection v2 (r21-proven): 128x64 tile, 768 blocks = 3/CU,
// 8 waves (4M x 2N), wave-tile 32x32. LDS 24KB. T1 swizzle. ----
__global__ __launch_bounds__(512) void o_gemm(const __bf16* __restrict__ A, const __bf16* __restrict__ W,
                                              const float* __restrict__ bias, float* __restrict__ Out) {
    __shared__ __attribute__((aligned(16))) char smem[24576];
    __bf16* As = (__bf16*)smem;
    __bf16* Bs = (__bf16*)(smem + 16384);

    const int h = (int)blockIdx.x;
    const int l = (h & 7) * 96 + (h >> 3);       // 768 % 8 == 0: bijective
    const int row0 = (l / 12) * 128, col0 = (l % 12) * 64;

    const int t = (int)threadIdx.x;
    const int lane = t & 63, w = t >> 6;
    const int l15 = lane & 15, lg = lane >> 4;
    const int wr = (w >> 1) * 32, wc = (w & 1) * 32;
    const int rl = lane >> 3, clin = lane & 7;

    f32x4 acc[2][2] = {};

    for (int k0 = 0; k0 < 768; k0 += 64) {
        __syncthreads();
#pragma unroll
        for (int o = 0; o < 2; ++o) {           // A: 16 ops of 8 rows
            const int g = w * 2 + o;
            const int r = g * 8 + rl;
            const int cg = clin ^ (r & 7);
            async_load16(A + (size_t)(row0 + r) * Dd + k0 + cg * 8, As + g * 512);
        }
        {                                        // B: 8 ops of 8 rows (one per wave)
            const int r = w * 8 + rl;
            const int cg = clin ^ (r & 7);
            async_load16(W + (size_t)(col0 + r) * Dd + k0 + cg * 8, Bs + w * 512);
        }
        __syncthreads();

        bfrag af[2][2], bf[2][2];
#pragma unroll
        for (int mi = 0; mi < 2; ++mi) {
            const int ra = wr + mi * 16 + l15;
#pragma unroll
            for (int ks = 0; ks < 2; ++ks)
                af[mi][ks] = *(const bfrag*)(As + ra * 64 + (((ks * 4 + lg) ^ (ra & 7)) * 8));
        }
#pragma unroll
        for (int ni = 0; ni < 2; ++ni) {
            const int rb = wc + ni * 16 + l15;
#pragma unroll
            for (int ks = 0; ks < 2; ++ks)
                bf[ni][ks] = *(const bfrag*)(Bs + rb * 64 + (((ks * 4 + lg) ^ (rb & 7)) * 8));
        }
#pragma unroll
        for (int mi = 0; mi < 2; ++mi)
#pragma unroll
            for (int ni = 0; ni < 2; ++ni)
#pragma unroll
                for (int ks = 0; ks < 2; ++ks)
                    acc[mi][ni] = __builtin_amdgcn_mfma_f32_16x16x32_bf16(af[mi][ks], bf[ni][ks],
                                                                          acc[mi][ni], 0, 0, 0);
    }

#pragma unroll
    for (int mi = 0; mi < 2; ++mi) {
#pragma unroll
        for (int ni = 0; ni < 2; ++ni) {
            const int cg = col0 + wc + ni * 16 + l15;
            const float bv = bias[cg];
#pragma unroll
            for (int j = 0; j < 4; ++j) {
                const int rg = row0 + wr + mi * 16 + lg * 4 + j;
                Out[(size_t)rg * Dd + cg] = acc[mi][ni][j] + bv;
            }
        }
    }
}

// ---- Flash attention v12 (r25-measured best): single-buffer K/V, 2 barriers
// per kt with split write-back, T2 XOR-swizzle (elem ^= (row&7)<<3) on all
// LDS tiles, NO-MAX base-2 softmax, deferred l-reduction, T14 + T5.
// 8 waves x 16 q-rows, 768 blocks, 96-bijective XCD grouping. ----
__global__ __launch_bounds__(512) void attn_k(const __bf16* __restrict__ q,
                                              const __bf16* __restrict__ k,
                                              const __bf16* __restrict__ vt,
                                              __bf16* __restrict__ o) {
    __shared__ __attribute__((aligned(16))) __bf16 Ks[64][64];        // [key][d] swizzled
    __shared__ __attribute__((aligned(16))) __bf16 Vs[64][64];        // [d][key] swizzled
    __shared__ __attribute__((aligned(16))) __bf16 plds[8][16][64];   // swizzled
    const int t = (int)threadIdx.x;
    const int lane = t & 63, w = t >> 6;          // w = 0..7
    const int l15 = lane & 15, lg = lane >> 4;
    const int blk = (int)blockIdx.x;
    const int bh = blk % 96, qt = blk / 96;       // 96 % 8 == 0: bijective XCD grouping
    const size_t bhb = (size_t)bh * Ss;
    const __bf16* qp = q + bhb * DKk;
    const __bf16* kp = k + bhb * DKk;
    const __bf16* vtp = vt + bhb * DKk;           // V^T: [64 d][1024 s]
    const int qbase = qt * 128 + w * 16;
    const int srow = t >> 3;                      // staging row 0..63
    const int scs = ((t & 7) ^ (srow & 7)) * 8;   // swizzled LDS chunk (elems)
    const int scg = (t & 7) * 8;                  // linear global chunk

    bfrag bq[2];
#pragma unroll
    for (int ks = 0; ks < 2; ++ks)
        bq[ks] = *reinterpret_cast<const bfrag*>(qp + (size_t)(qbase + l15) * DKk + ks * 32 + lg * 8);

    float lpart = 0.f;           // per-lane PARTIAL denom (own 16 keys per kt)
    f32x4 oacc[4] = {};

    {   // prologue: stage tile 0 (one b128 per thread per tensor)
        bfrag k0 = *reinterpret_cast<const bfrag*>(kp + (size_t)srow * DKk + scg);
        bfrag v0 = *reinterpret_cast<const bfrag*>(vtp + (size_t)srow * Ss + scg);
        *reinterpret_cast<bfrag*>(&Ks[srow][scs]) = k0;
        *reinterpret_cast<bfrag*>(&Vs[srow][scs]) = v0;
    }
    __syncthreads();

    for (int kt = 0; kt < 16; ++kt) {
        // T14: issue next tile's global loads BEFORE compute
        bfrag kn, vn;
        if (kt < 15) {
            const int kb1 = (kt + 1) * 64;
            kn = *reinterpret_cast<const bfrag*>(kp + (size_t)(kb1 + srow) * DKk + scg);
            vn = *reinterpret_cast<const bfrag*>(vtp + (size_t)srow * Ss + kb1 + scg);
        }

        // QK^T swapped: sacc[n][j]: key = n*16+lg*4+j, q = l15
        f32x4 sacc[4] = {};
        __builtin_amdgcn_s_setprio(1);
#pragma unroll
        for (int n = 0; n < 4; ++n) {
#pragma unroll
            for (int ks = 0; ks < 2; ++ks) {
                const bfrag ak = *reinterpret_cast<const bfrag*>(
                    &Ks[n * 16 + l15][(ks * 32 + lg * 8) ^ ((l15 & 7) << 3)]);
                sacc[n] = __builtin_amdgcn_mfma_f32_16x16x32_bf16(ak, bq[ks], sacc[n], 0, 0, 0);
            }
        }
        __builtin_amdgcn_s_setprio(0);

        __syncthreads();   // BARa: all QK reads of Ks complete
        if (kt < 15)
            *reinterpret_cast<bfrag*>(&Ks[srow][scs]) = kn;   // overlaps softmax+PV

        // no-max softmax: p = exp2(s); per-lane partial denom (no shuffles)
        float p[4][4];
        float rs = 0.f;
#pragma unroll
        for (int n = 0; n < 4; ++n)
#pragma unroll
            for (int j = 0; j < 4; ++j) {
                const float pe = EXP2(sacc[n][j]);
                p[n][j] = pe;
                rs += pe;
            }
        lpart += rs;

        // P -> wave-private LDS, packed b64, swizzled by q-row (l15)
#pragma unroll
        for (int n = 0; n < 4; ++n) {
            bf16x4 pk;
#pragma unroll
            for (int j = 0; j < 4; ++j) pk[j] = (__bf16)p[n][j];
            *reinterpret_cast<bf16x4*>(
                &plds[w][l15][(n * 16 + lg * 4) ^ ((l15 & 7) << 3)]) = pk;
        }

        // PV: A = P (swizzled read), B = V^T tile in LDS (swizzled read)
        __builtin_amdgcn_s_setprio(1);
#pragma unroll
        for (int ks = 0; ks < 2; ++ks) {
            const bfrag ap = *reinterpret_cast<const bfrag*>(
                &plds[w][l15][(ks * 32 + lg * 8) ^ ((l15 & 7) << 3)]);
#pragma unroll
            for (int dt = 0; dt < 4; ++dt) {
                const bfrag bv = *reinterpret_cast<const bfrag*>(
                    &Vs[dt * 16 + l15][(ks * 32 + lg * 8) ^ ((l15 & 7) << 3)]);
                oacc[dt] = __builtin_amdgcn_mfma_f32_16x16x32_bf16(ap, bv, oacc[dt], 0, 0, 0);
            }
        }
        __builtin_amdgcn_s_setprio(0);

        __syncthreads();   // BARb: all PV reads of Vs complete; seals Ks write
        if (kt < 15)
            *reinterpret_cast<bfrag*>(&Vs[srow][scs]) = vn;   // sealed by next BARa
    }

    // epilogue: reduce denom across lg ONCE, then divide and write [B,S,D]
    float lrow = lpart;
    lrow += __shfl_xor(lrow, 16);
    lrow += __shfl_xor(lrow, 32);
    float linv[4];
#pragma unroll
    for (int j = 0; j < 4; ++j) linv[j] = 1.0f / __shfl(lrow, lg * 4 + j);
    const int bb = bh / Hh, hh = bh % Hh;
#pragma unroll
    for (int dt = 0; dt < 4; ++dt)
#pragma unroll
        for (int j = 0; j < 4; ++j) {
            const int qrow = qbase + lg * 4 + j;
            o[((size_t)(bb * Ss + qrow)) * Dd + hh * DKk + dt * 16 + l15] =
                (__bf16)(oacc[dt][j] * linv[j]);
        }
}

extern "C" void kernel_launch(void* const* d_in, const int* in_sizes, int n_in,
                              void* d_out, int out_size, void* d_ws, size_t ws_size,
                              hipStream_t stream) {
    (void)in_sizes; (void)n_in; (void)out_size; (void)ws_size;
    // dict order: key, query, value, Wk, bk, Wq, bq, Wv, bv, Wo, bo
    const float* key   = (const float*)d_in[0];
    const float* query = (const float*)d_in[1];
    const float* value = (const float*)d_in[2];
    const float* Wk = (const float*)d_in[3];
    const float* bk = (const float*)d_in[4];
    const float* Wq = (const float*)d_in[5];
    const float* bq = (const float*)d_in[6];
    const float* Wv = (const float*)d_in[7];
    const float* bvp = (const float*)d_in[8];
    const float* Wo = (const float*)d_in[9];
    const float* bo = (const float*)d_in[10];

    const size_t NA = (size_t)Mm * Dd;   // 6291456 activation elems
    const size_t NW = (size_t)Dd * Dd;   // 589824 weight elems
    __bf16* p = (__bf16*)d_ws;
    __bf16* qab = p;            p += NA;   // bf16 query
    __bf16* kab = p;            p += NA;   // bf16 key
    __bf16* vab = p;            p += NA;   // bf16 value
    __bf16* wqb = p;            p += NW;
    __bf16* wkb = p;            p += NW;
    __bf16* wvb = p;            p += NW;
    __bf16* wob = p;            p += NW;
    __bf16* qws = p;            p += NA;   // Q proj (scaled by 0.125*log2e)
    __bf16* kws = p;            p += NA;   // K proj
    __bf16* vtws = p;           p += NA;   // V^T proj
    __bf16* aws = qab;                     // attn out aliases dead qab

    dim3 b256(256), b512(512);
    cvt_k<<<dim3(10368), b256, 0, stream>>>(query, key, value, Wq, Wk, Wv, Wo,
                                            qab, kab, vab, wqb, wkb, wvb, wob);
    qkv_gemm<<<dim3(1152), b512, 0, stream>>>(qab, kab, vab,
                                              wqb, wkb, wvb,
                                              bq, bk, bvp,
                                              qws, kws, vtws);
    attn_k<<<dim3(Ss / 128 * Hh * Bb), b512, 0, stream>>>(qws, kws, vtws, aws);
    o_gemm<<<dim3(768), b512, 0, stream>>>(aws, wob, bo, (float*)d_out);
}

// Round 28
// 102.433 us; speedup vs baseline: 1.0173x; 1.0173x over previous
//
#include <hip/hip_runtime.h>
#include <stdint.h>

#define DI __device__ __forceinline__

typedef __attribute__((ext_vector_type(8))) __bf16 bfrag;   // MFMA A/B operand (4 VGPRs)
typedef __attribute__((ext_vector_type(4))) __bf16 bf16x4;
typedef __attribute__((ext_vector_type(4))) float f32x4;    // MFMA C/D operand

static constexpr int Bb = 8, Ss = 1024, Dd = 768, Hh = 12, DKk = 64;
static constexpr int Mm = Bb * Ss;          // 8192 rows

typedef __attribute__((address_space(3))) void lds_void_t;
typedef const __attribute__((address_space(1))) void gvoid_t;

DI void async_load16(const void* g, void* lds) {
    __builtin_amdgcn_global_load_lds((gvoid_t*)(uintptr_t)g,
                                     (lds_void_t*)(uint32_t)(uintptr_t)lds, 16, 0, 0);
}

#if __has_builtin(__builtin_amdgcn_exp2f)
#define EXP2(x) __builtin_amdgcn_exp2f(x)
#else
extern "C" __device__ float __ocml_exp2_f32(float);
#define EXP2(x) __ocml_exp2_f32(x)
#endif

// ---- fp32 -> bf16 convert, all 7 tensors in ONE launch ----
__global__ __launch_bounds__(256) void cvt_k(const float* __restrict__ a0, const float* __restrict__ a1,
                                             const float* __restrict__ a2,
                                             const float* __restrict__ w0, const float* __restrict__ w1,
                                             const float* __restrict__ w2, const float* __restrict__ w3,
                                             __bf16* __restrict__ da0, __bf16* __restrict__ da1,
                                             __bf16* __restrict__ da2,
                                             __bf16* __restrict__ dw0, __bf16* __restrict__ dw1,
                                             __bf16* __restrict__ dw2, __bf16* __restrict__ dw3) {
    const int bid = (int)blockIdx.x;
    const float* s; __bf16* d; int off;
    if (bid < 9216) {
        const int ti = bid / 3072;
        off = (bid % 3072) * 2048;
        s = ti == 0 ? a0 : ti == 1 ? a1 : a2;
        d = ti == 0 ? da0 : ti == 1 ? da1 : da2;
    } else {
        const int b2 = bid - 9216;
        const int ti = b2 / 288;
        off = (b2 % 288) * 2048;
        s = ti == 0 ? w0 : ti == 1 ? w1 : ti == 2 ? w2 : w3;
        d = ti == 0 ? dw0 : ti == 1 ? dw1 : ti == 2 ? dw2 : dw3;
    }
    const int i = off + (int)threadIdx.x * 8;
    f32x4 a = *(const f32x4*)(s + i);
    f32x4 b = *(const f32x4*)(s + i + 4);
    bfrag o;
#pragma unroll
    for (int j = 0; j < 4; ++j) { o[j] = (__bf16)a[j]; o[j + 4] = (__bf16)b[j]; }
    *(bfrag*)(d + i) = o;
}

// ---- GEMM core v6 (r19-proven): 128x128 tile, BK=64, 2-barrier loop,
// 512 threads = 8 waves, wave-tile 64x32. bf16 A via global_load_lds. ----
DI void gemm_core8(const __bf16* __restrict__ A, const __bf16* __restrict__ W,
                   __bf16* As, __bf16* Bs, int row0, int col0, int t, f32x4 acc[4][2]) {
    const int lane = t & 63, w = t >> 6;          // w = 0..7
    const int l15 = lane & 15, lg = lane >> 4;
    const int wr = (w >> 2) * 64, wc = (w & 3) * 32;
    const int rl = lane >> 3, clin = lane & 7;    // staging: row-in-op, linear chunk

    for (int k0 = 0; k0 < 768; k0 += 64) {
        __syncthreads();   // all waves done reading previous tile
#pragma unroll
        for (int o = 0; o < 2; ++o) {
            const int g = w * 2 + o;              // op id 0..15, wave-uniform
            const int r = g * 8 + rl;             // tile row 0..127
            const int cg = clin ^ (r & 7);        // pre-swizzled global chunk
            async_load16(A + (size_t)(row0 + r) * Dd + k0 + cg * 8, As + g * 512);
            async_load16(W + (size_t)(col0 + r) * Dd + k0 + cg * 8, Bs + g * 512);
        }
        __syncthreads();   // compiler drains vmcnt before barrier -> LDS visible

        bfrag af[4][2], bf[2][2];
#pragma unroll
        for (int mi = 0; mi < 4; ++mi) {
            const int ra = wr + mi * 16 + l15;
#pragma unroll
            for (int ks = 0; ks < 2; ++ks)
                af[mi][ks] = *(const bfrag*)(As + ra * 64 + (((ks * 4 + lg) ^ (ra & 7)) * 8));
        }
#pragma unroll
        for (int ni = 0; ni < 2; ++ni) {
            const int rb = wc + ni * 16 + l15;
#pragma unroll
            for (int ks = 0; ks < 2; ++ks)
                bf[ni][ks] = *(const bfrag*)(Bs + rb * 64 + (((ks * 4 + lg) ^ (rb & 7)) * 8));
        }
#pragma unroll
        for (int mi = 0; mi < 4; ++mi)
#pragma unroll
            for (int ni = 0; ni < 2; ++ni)
#pragma unroll
                for (int ks = 0; ks < 2; ++ks)
                    acc[mi][ni] = __builtin_amdgcn_mfma_f32_16x16x32_bf16(af[mi][ks], bf[ni][ks],
                                                                          acc[mi][ni], 0, 0, 0);
    }
}

// ---- fused QKV projection: 1-D grid 1152, 512 threads, T1 XCD-bijective
// (contiguous z = l/384 — r27's z-interleave broke A/W L2 locality).
// z=0: Q (scaled 0.125*log2e); z=1: K; z=2: V -> V^T [B,H,64,S].
__global__ __launch_bounds__(512) void qkv_gemm(const __bf16* __restrict__ qA, const __bf16* __restrict__ kA,
                                                const __bf16* __restrict__ vA,
                                                const __bf16* __restrict__ qW, const __bf16* __restrict__ kW,
                                                const __bf16* __restrict__ vW,
                                                const float* __restrict__ qb, const float* __restrict__ kb,
                                                const float* __restrict__ vb,
                                                __bf16* __restrict__ qO, __bf16* __restrict__ kO,
                                                __bf16* __restrict__ vO) {
    __shared__ __attribute__((aligned(16))) char smem[32768];
    __bf16* As = (__bf16*)smem;
    __bf16* Bs = (__bf16*)(smem + 16384);

    const int h = (int)blockIdx.x;
    const int l = (h & 7) * 144 + (h >> 3);      // 1152 % 8 == 0: bijective
    const int z = l / 384, r2 = l % 384;
    const int row0 = (r2 / 6) * 128, col0 = (r2 % 6) * 128;

    const __bf16* A = z == 0 ? qA : z == 1 ? kA : vA;
    const __bf16* W = z == 0 ? qW : z == 1 ? kW : vW;
    const float* bias = z == 0 ? qb : z == 1 ? kb : vb;
    __bf16* O = z == 0 ? qO : z == 1 ? kO : vO;

    const int t = (int)threadIdx.x;
    const int lane = t & 63, w = t >> 6;
    const int l15 = lane & 15, lg = lane >> 4;
    const int wr = (w >> 2) * 64, wc = (w & 3) * 32;

    f32x4 acc[4][2] = {};
    gemm_core8(A, W, As, Bs, row0, col0, t, acc);

    if (z == 2) {
        // V^T epilogue, two half-passes over d-cols. Half dh covers cols
        // dh*64..dh*64+63; waves with (w&2)>>1 == dh hold them.
        auto T = reinterpret_cast<__bf16(*)[136]>(smem);   // [64 d][136 pad s]
        const int bb2 = row0 >> 10, sb = row0 & 1023;
#pragma unroll
        for (int dh = 0; dh < 2; ++dh) {
            __syncthreads();
            if (((w >> 1) & 1) == dh) {
#pragma unroll
                for (int mi = 0; mi < 4; ++mi)
#pragma unroll
                    for (int ni = 0; ni < 2; ++ni) {
                        const int dcol = (w & 1) * 32 + ni * 16 + l15;   // 0..63 in half
                        const float bv = bias[col0 + dh * 64 + dcol];
#pragma unroll
                        for (int j = 0; j < 4; ++j)
                            T[dcol][wr + mi * 16 + lg * 4 + j] = (__bf16)(acc[mi][ni][j] + bv);
                    }
            }
            __syncthreads();
#pragma unroll
            for (int it = 0; it < 2; ++it) {
                const int ld = it * 32 + (t >> 4);                 // 0..63
                const int cs = (t & 15) * 8;                       // s-chunk
                const int col = col0 + dh * 64 + ld;
                const int head = col >> 6, dd = col & 63;
                __bf16* dst = O + ((size_t)(bb2 * Hh + head) * DKk + dd) * Ss + sb + cs;
                *reinterpret_cast<bfrag*>(dst) = *reinterpret_cast<const bfrag*>(&T[ld][cs]);
            }
        }
    } else {
        const float scl = (z == 0) ? 0.18033688f : 1.0f;  // 0.125 * log2(e)
#pragma unroll
        for (int mi = 0; mi < 4; ++mi) {
#pragma unroll
            for (int ni = 0; ni < 2; ++ni) {
                const int cg = col0 + wc + ni * 16 + l15;
                const float bv = bias[cg];
#pragma unroll
                for (int j = 0; j < 4; ++j) {
                    const int rg = row0 + wr + mi * 16 + lg * 4 + j;
                    const float val = (acc[mi][ni][j] + bv) * scl;
                    const int bb = rg >> 10, ss = rg & 1023;
                    const int hh2 = cg >> 6, dd = cg & 63;
                    O[((size_t)(bb * Hh + hh2) * Ss + ss) * DKk + dd] = (__bf16)val;
                }
            }
        }
    }
}

// ---- output projection v2 (r21-proven): 128x64 tile, 768 blocks = 3/CU,
// 8 waves (4M x 2N), wave-tile 32x32. LDS 24KB. T1 swizzle. ----
__global__ __launch_bounds__(512) void o_gemm(const __bf16* __restrict__ A, const __bf16* __restrict__ W,
                                              const float* __restrict__ bias, float* __restrict__ Out) {
    __shared__ __attribute__((aligned(16))) char smem[24576];
    __bf16* As = (__bf16*)smem;
    __bf16* Bs = (__bf16*)(smem + 16384);

    const int h = (int)blockIdx.x;
    const int l = (h & 7) * 96 + (h >> 3);       // 768 % 8 == 0: bijective
    const int row0 = (l / 12) * 128, col0 = (l % 12) * 64;

    const int t = (int)threadIdx.x;
    const int lane = t & 63, w = t >> 6;
    const int l15 = lane & 15, lg = lane >> 4;
    const int wr = (w >> 1) * 32, wc = (w & 1) * 32;
    const int rl = lane >> 3, clin = lane & 7;

    f32x4 acc[2][2] = {};

    for (int k0 = 0; k0 < 768; k0 += 64) {
        __syncthreads();
#pragma unroll
        for (int o = 0; o < 2; ++o) {           // A: 16 ops of 8 rows
            const int g = w * 2 + o;
            const int r = g * 8 + rl;
            const int cg = clin ^ (r & 7);
            async_load16(A + (size_t)(row0 + r) * Dd + k0 + cg * 8, As + g * 512);
        }
        {                                        // B: 8 ops of 8 rows (one per wave)
            const int r = w * 8 + rl;
            const int cg = clin ^ (r & 7);
            async_load16(W + (size_t)(col0 + r) * Dd + k0 + cg * 8, Bs + w * 512);
        }
        __syncthreads();

        bfrag af[2][2], bf[2][2];
#pragma unroll
        for (int mi = 0; mi < 2; ++mi) {
            const int ra = wr + mi * 16 + l15;
#pragma unroll
            for (int ks = 0; ks < 2; ++ks)
                af[mi][ks] = *(const bfrag*)(As + ra * 64 + (((ks * 4 + lg) ^ (ra & 7)) * 8));
        }
#pragma unroll
        for (int ni = 0; ni < 2; ++ni) {
            const int rb = wc + ni * 16 + l15;
#pragma unroll
            for (int ks = 0; ks < 2; ++ks)
                bf[ni][ks] = *(const bfrag*)(Bs + rb * 64 + (((ks * 4 + lg) ^ (rb & 7)) * 8));
        }
#pragma unroll
        for (int mi = 0; mi < 2; ++mi)
#pragma unroll
            for (int ni = 0; ni < 2; ++ni)
#pragma unroll
                for (int ks = 0; ks < 2; ++ks)
                    acc[mi][ni] = __builtin_amdgcn_mfma_f32_16x16x32_bf16(af[mi][ks], bf[ni][ks],
                                                                          acc[mi][ni], 0, 0, 0);
    }

#pragma unroll
    for (int mi = 0; mi < 2; ++mi) {
#pragma unroll
        for (int ni = 0; ni < 2; ++ni) {
            const int cg = col0 + wc + ni * 16 + l15;
            const float bv = bias[cg];
#pragma unroll
            for (int j = 0; j < 4; ++j) {
                const int rg = row0 + wr + mi * 16 + lg * 4 + j;
                Out[(size_t)rg * Dd + cg] = acc[mi][ni][j] + bv;
            }
        }
    }
}

// ---- Flash attention v12 (r25-measured best): single-buffer K/V, 2 barriers
// per kt with split write-back, T2 XOR-swizzle (elem ^= (row&7)<<3) on all
// LDS tiles, NO-MAX base-2 softmax, deferred l-reduction, T14 + T5.
// 8 waves x 16 q-rows, 768 blocks, 96-bijective XCD grouping. ----
__global__ __launch_bounds__(512) void attn_k(const __bf16* __restrict__ q,
                                              const __bf16* __restrict__ k,
                                              const __bf16* __restrict__ vt,
                                              __bf16* __restrict__ o) {
    __shared__ __attribute__((aligned(16))) __bf16 Ks[64][64];        // [key][d] swizzled
    __shared__ __attribute__((aligned(16))) __bf16 Vs[64][64];        // [d][key] swizzled
    __shared__ __attribute__((aligned(16))) __bf16 plds[8][16][64];   // swizzled
    const int t = (int)threadIdx.x;
    const int lane = t & 63, w = t >> 6;          // w = 0..7
    const int l15 = lane & 15, lg = lane >> 4;
    const int blk = (int)blockIdx.x;
    const int bh = blk % 96, qt = blk / 96;       // 96 % 8 == 0: bijective XCD grouping
    const size_t bhb = (size_t)bh * Ss;
    const __bf16* qp = q + bhb * DKk;
    const __bf16* kp = k + bhb * DKk;
    const __bf16* vtp = vt + bhb * DKk;           // V^T: [64 d][1024 s]
    const int qbase = qt * 128 + w * 16;
    const int srow = t >> 3;                      // staging row 0..63
    const int scs = ((t & 7) ^ (srow & 7)) * 8;   // swizzled LDS chunk (elems)
    const int scg = (t & 7) * 8;                  // linear global chunk

    bfrag bq[2];
#pragma unroll
    for (int ks = 0; ks < 2; ++ks)
        bq[ks] = *reinterpret_cast<const bfrag*>(qp + (size_t)(qbase + l15) * DKk + ks * 32 + lg * 8);

    float lpart = 0.f;           // per-lane PARTIAL denom (own 16 keys per kt)
    f32x4 oacc[4] = {};

    {   // prologue: stage tile 0 (one b128 per thread per tensor)
        bfrag k0 = *reinterpret_cast<const bfrag*>(kp + (size_t)srow * DKk + scg);
        bfrag v0 = *reinterpret_cast<const bfrag*>(vtp + (size_t)srow * Ss + scg);
        *reinterpret_cast<bfrag*>(&Ks[srow][scs]) = k0;
        *reinterpret_cast<bfrag*>(&Vs[srow][scs]) = v0;
    }
    __syncthreads();

    for (int kt = 0; kt < 16; ++kt) {
        // T14: issue next tile's global loads BEFORE compute
        bfrag kn, vn;
        if (kt < 15) {
            const int kb1 = (kt + 1) * 64;
            kn = *reinterpret_cast<const bfrag*>(kp + (size_t)(kb1 + srow) * DKk + scg);
            vn = *reinterpret_cast<const bfrag*>(vtp + (size_t)srow * Ss + kb1 + scg);
        }

        // QK^T swapped: sacc[n][j]: key = n*16+lg*4+j, q = l15
        f32x4 sacc[4] = {};
        __builtin_amdgcn_s_setprio(1);
#pragma unroll
        for (int n = 0; n < 4; ++n) {
#pragma unroll
            for (int ks = 0; ks < 2; ++ks) {
                const bfrag ak = *reinterpret_cast<const bfrag*>(
                    &Ks[n * 16 + l15][(ks * 32 + lg * 8) ^ ((l15 & 7) << 3)]);
                sacc[n] = __builtin_amdgcn_mfma_f32_16x16x32_bf16(ak, bq[ks], sacc[n], 0, 0, 0);
            }
        }
        __builtin_amdgcn_s_setprio(0);

        __syncthreads();   // BARa: all QK reads of Ks complete
        if (kt < 15)
            *reinterpret_cast<bfrag*>(&Ks[srow][scs]) = kn;   // overlaps softmax+PV

        // no-max softmax: p = exp2(s); per-lane partial denom (no shuffles)
        float p[4][4];
        float rs = 0.f;
#pragma unroll
        for (int n = 0; n < 4; ++n)
#pragma unroll
            for (int j = 0; j < 4; ++j) {
                const float pe = EXP2(sacc[n][j]);
                p[n][j] = pe;
                rs += pe;
            }
        lpart += rs;

        // P -> wave-private LDS, packed b64, swizzled by q-row (l15)
#pragma unroll
        for (int n = 0; n < 4; ++n) {
            bf16x4 pk;
#pragma unroll
            for (int j = 0; j < 4; ++j) pk[j] = (__bf16)p[n][j];
            *reinterpret_cast<bf16x4*>(
                &plds[w][l15][(n * 16 + lg * 4) ^ ((l15 & 7) << 3)]) = pk;
        }

        // PV: A = P (swizzled read), B = V^T tile in LDS (swizzled read)
        __builtin_amdgcn_s_setprio(1);
#pragma unroll
        for (int ks = 0; ks < 2; ++ks) {
            const bfrag ap = *reinterpret_cast<const bfrag*>(
                &plds[w][l15][(ks * 32 + lg * 8) ^ ((l15 & 7) << 3)]);
#pragma unroll
            for (int dt = 0; dt < 4; ++dt) {
                const bfrag bv = *reinterpret_cast<const bfrag*>(
                    &Vs[dt * 16 + l15][(ks * 32 + lg * 8) ^ ((l15 & 7) << 3)]);
                oacc[dt] = __builtin_amdgcn_mfma_f32_16x16x32_bf16(ap, bv, oacc[dt], 0, 0, 0);
            }
        }
        __builtin_amdgcn_s_setprio(0);

        __syncthreads();   // BARb: all PV reads of Vs complete; seals Ks write
        if (kt < 15)
            *reinterpret_cast<bfrag*>(&Vs[srow][scs]) = vn;   // sealed by next BARa
    }

    // epilogue: reduce denom across lg ONCE, then divide and write [B,S,D]
    float lrow = lpart;
    lrow += __shfl_xor(lrow, 16);
    lrow += __shfl_xor(lrow, 32);
    float linv[4];
#pragma unroll
    for (int j = 0; j < 4; ++j) linv[j] = 1.0f / __shfl(lrow, lg * 4 + j);
    const int bb = bh / Hh, hh = bh % Hh;
#pragma unroll
    for (int dt = 0; dt < 4; ++dt)
#pragma unroll
        for (int j = 0; j < 4; ++j) {
            const int qrow = qbase + lg * 4 + j;
            o[((size_t)(bb * Ss + qrow)) * Dd + hh * DKk + dt * 16 + l15] =
                (__bf16)(oacc[dt][j] * linv[j]);
        }
}

extern "C" void kernel_launch(void* const* d_in, const int* in_sizes, int n_in,
                              void* d_out, int out_size, void* d_ws, size_t ws_size,
                              hipStream_t stream) {
    (void)in_sizes; (void)n_in; (void)out_size; (void)ws_size;
    // dict order: key, query, value, Wk, bk, Wq, bq, Wv, bv, Wo, bo
    const float* key   = (const float*)d_in[0];
    const float* query = (const float*)d_in[1];
    const float* value = (const float*)d_in[2];
    const float* Wk = (const float*)d_in[3];
    const float* bk = (const float*)d_in[4];
    const float* Wq = (const float*)d_in[5];
    const float* bq = (const float*)d_in[6];
    const float* Wv = (const float*)d_in[7];
    const float* bvp = (const float*)d_in[8];
    const float* Wo = (const float*)d_in[9];
    const float* bo = (const float*)d_in[10];

    const size_t NA = (size_t)Mm * Dd;   // 6291456 activation elems
    const size_t NW = (size_t)Dd * Dd;   // 589824 weight elems
    __bf16* p = (__bf16*)d_ws;
    __bf16* qab = p;            p += NA;   // bf16 query
    __bf16* kab = p;            p += NA;   // bf16 key
    __bf16* vab = p;            p += NA;   // bf16 value
    __bf16* wqb = p;            p += NW;
    __bf16* wkb = p;            p += NW;
    __bf16* wvb = p;            p += NW;
    __bf16* wob = p;            p += NW;
    __bf16* qws = p;            p += NA;   // Q proj (scaled by 0.125*log2e)
    __bf16* kws = p;            p += NA;   // K proj
    __bf16* vtws = p;           p += NA;   // V^T proj
    __bf16* aws = qab;                     // attn out aliases dead qab

    dim3 b256(256), b512(512);
    cvt_k<<<dim3(10368), b256, 0, stream>>>(query, key, value, Wq, Wk, Wv, Wo,
                                            qab, kab, vab, wqb, wkb, wvb, wob);
    qkv_gemm<<<dim3(1152), b512, 0, stream>>>(qab, kab, vab,
                                              wqb, wkb, wvb,
                                              bq, bk, bvp,
                                              qws, kws, vtws);
    attn_k<<<dim3(Ss / 128 * Hh * Bb), b512, 0, stream>>>(qws, kws, vtws, aws);
    o_gemm<<<dim3(768), b512, 0, stream>>>(aws, wob, bo, (float*)d_out);
}